// Round 12
// baseline (544.124 us; speedup 1.0000x reference)
//
#include <hip/hip_runtime.h>
#include <hip/hip_bf16.h>
#include <stdint.h>
#include <math.h>

typedef __bf16 bf16_t;
typedef __bf16 bf16x8 __attribute__((ext_vector_type(8)));
typedef __bf16 bf16x4 __attribute__((ext_vector_type(4)));
typedef float  f32x4  __attribute__((ext_vector_type(4)));

typedef __attribute__((address_space(1))) const void global_cv;
typedef __attribute__((address_space(3))) void lds_v;

// Problem constants: B=16,H=64,W=80,C=256; GH=8,GW=10; heads=8,DH=32; INNER=1024

__device__ __forceinline__ int map_p_to_g(int p) {
    int w = p / 80, n = p - w * 80;
    int b  = w >> 6, h2 = (w >> 3) & 7, w2 = w & 7;
    int gh = n / 10, gw = n - gh * 10;
    return b * 5120 + (gh * 8 + h2) * 80 + (gw * 8 + w2);
}

// XOR swizzle for 64-B LDS rows: slot bits 4-5 ^= row bits 1-2 (byte bits 7-8).
// Involution, keeps 16B align; 16 lanes reading same slot across rows -> 2 lanes/bank.
__device__ __forceinline__ int swz64(int b) { return b ^ (((b >> 7) & 3) << 4); }

// ---------------- weight convert+transpose: fp32 [K][N] -> bf16 [N][K] ----------------
__global__ __launch_bounds__(256) void wconv_k(const float* __restrict__ in,
                                               bf16_t* __restrict__ out, int N, int K)
{
    int i = blockIdx.x * 256 + threadIdx.x;
    int n = i / K, k = i - n * K;
    out[i] = (bf16_t)in[(size_t)k * N + n];
}

// ---------------- LayerNorm (one wave per row), optional partition permute ----------------
template <int PERM>
__global__ __launch_bounds__(256) void ln_k(const float* __restrict__ in,
                                            const float* __restrict__ gg,
                                            const float* __restrict__ bb,
                                            bf16_t* __restrict__ o)
{
    int row  = blockIdx.x * 4 + (threadIdx.x >> 6);
    int lane = threadIdx.x & 63;
    const float4 xv = *(const float4*)(in + (size_t)row * 256 + lane * 4);
    float s = xv.x + xv.y + xv.z + xv.w;
#pragma unroll
    for (int m = 1; m < 64; m <<= 1) s += __shfl_xor(s, m, 64);
    float mean = s * (1.f / 256.f);
    float d0 = xv.x - mean, d1 = xv.y - mean, d2 = xv.z - mean, d3 = xv.w - mean;
    float v = d0 * d0 + d1 * d1 + d2 * d2 + d3 * d3;
#pragma unroll
    for (int m = 1; m < 64; m <<= 1) v += __shfl_xor(v, m, 64);
    float rstd = rsqrtf(v * (1.f / 256.f) + 1e-5f);
    const float4 gv = *(const float4*)(gg + lane * 4);
    const float4 bv = *(const float4*)(bb + lane * 4);
    int orow = row;
    if (PERM) {
        int b = row / 5120, r1 = row - b * 5120;
        int h = r1 / 80, wv = r1 - h * 80;
        int gh = h >> 3, h2 = h & 7, gw = wv >> 3, w2 = wv & 7;
        orow = ((b * 8 + h2) * 8 + w2) * 80 + gh * 10 + gw;
    }
    bf16x4 ov;
    ov[0] = (bf16_t)(d0 * rstd * gv.x + bv.x);
    ov[1] = (bf16_t)(d1 * rstd * gv.y + bv.y);
    ov[2] = (bf16_t)(d2 * rstd * gv.z + bv.z);
    ov[3] = (bf16_t)(d3 * rstd * gv.w + bv.w);
    *(bf16x4*)(o + (size_t)orow * 256 + lane * 4) = ov;
}

// ---------------- 256x256-tile MFMA GEMM, counted-vmcnt pipeline (T3/T4) ----------------
// BK=32, 4 LDS buffers (128 KB), prefetch 3 tiles ahead. Per step:
//   {vmcnt(8) [oldest stage retired, 2 stages stay IN FLIGHT across the barrier];
//    raw s_barrier (memory-fenced asm, no drain); stage(s+3); 12 ds_read + 32 MFMA/wave}
// Swapped mfma operands (bv,av): our row = ln, our cols = kg*4+r -> vectorized epilogue.
// EPI 0: bf16 out (+bias) [qkv]; 1: fp32 x[g]+ls*(acc+b), grid-reverse [proj];
// EPI 2: bf16 gelu_sig    [fc1]; 3: fp32 out += ls*(acc+b) [fc2]
template <int EPI, int NBX>
__device__ __forceinline__ void gemm_body(const bf16_t* __restrict__ A,
                                          const bf16_t* __restrict__ Bt,
                                          const float* __restrict__ bias,
                                          const float* __restrict__ xres,
                                          const float* __restrict__ ls,
                                          void* __restrict__ outp,
                                          int N, int K)
{
    __shared__ bf16_t At[4][8192];   // 4 bufs x [256 rows x 64 B]
    __shared__ bf16_t Bl[4][8192];
    const int t = threadIdx.x;
    const int wid = t >> 6, lane = t & 63;
    const int wr = wid >> 2, wc = wid & 3;
    const int ln = lane & 15, kg = lane >> 4;

    // bijective XCD swizzle: grid = NBY*NBX, NBY multiple of 8
    const int f   = blockIdx.x;
    const int xcd = f & 7, jj = f >> 3;
    const int byx = (gridDim.x >> 3) / NBX;
    const int by  = xcd * byx + jj / NBX;
    const int bx  = jj % NBX;

    const size_t Kb = (size_t)K * 2;
    const char* Ab = (const char*)(A  + (size_t)by * 256 * K);
    const char* Bb = (const char*)(Bt + (size_t)bx * 256 * K);
    char* AtB = (char*)At;
    char* BlB = (char*)Bl;

    const f32x4 fz = {0.f, 0.f, 0.f, 0.f};
    f32x4 acc[8][4];
#pragma unroll
    for (int i = 0; i < 8; ++i)
#pragma unroll
        for (int j = 0; j < 4; ++j) acc[i][j] = fz;

    const int nsteps = K >> 5;   // BK=32

    // stage one 32-KB K-slice (16 KB A + 16 KB B); 4 gload_lds per thread
    auto stage = [&](int s, int buf) {
        const size_t kb = (size_t)s * 64;
        char* Ad = AtB + buf * 16384;
        char* Bd = BlB + buf * 16384;
#pragma unroll
        for (int i = 0; i < 2; ++i) {
            int p   = i * 8192 + t * 16;
            int sem = swz64(p);                  // inverse-swizzled source (rule 21)
            int row = sem >> 6;
            int off = sem & 63;
            __builtin_amdgcn_global_load_lds((global_cv*)(Ab + (size_t)row * Kb + kb + off),
                                             (lds_v*)(Ad + p), 16, 0, 0);
            __builtin_amdgcn_global_load_lds((global_cv*)(Bb + (size_t)row * Kb + kb + off),
                                             (lds_v*)(Bd + p), 16, 0, 0);
        }
    };

    stage(0, 0);
    if (nsteps > 1) stage(1, 1);
    if (nsteps > 2) stage(2, 2);

    for (int s = 0; s < nsteps; ++s) {
        // wait for stage(s) only; stages s+1,s+2 remain in flight across the barrier
        if (s + 2 < nsteps)      asm volatile("s_waitcnt vmcnt(8)" ::: "memory");
        else if (s + 1 < nsteps) asm volatile("s_waitcnt vmcnt(4)" ::: "memory");
        else                     asm volatile("s_waitcnt vmcnt(0)" ::: "memory");
        asm volatile("s_barrier" ::: "memory");   // raw barrier: no vmcnt(0) drain

        if (s + 3 < nsteps) stage(s + 3, (s + 3) & 3);   // issue-early (T14)

        const char* Ac = AtB + (s & 3) * 16384;
        const char* Bc = BlB + (s & 3) * 16384;
        bf16x8 av[8], bv[4];
#pragma unroll
        for (int mt = 0; mt < 8; ++mt) {
            int row = wr * 128 + mt * 16 + ln;
            av[mt] = *(const bf16x8*)(Ac + swz64(row * 64 + kg * 16));
        }
#pragma unroll
        for (int nt = 0; nt < 4; ++nt) {
            int row = wc * 64 + nt * 16 + ln;
            bv[nt] = *(const bf16x8*)(Bc + swz64(row * 64 + kg * 16));
        }
        // swapped operands: D^T layout -> our row=ln, our cols=kg*4+r
#pragma unroll
        for (int mt = 0; mt < 8; ++mt)
#pragma unroll
            for (int nt = 0; nt < 4; ++nt)
                acc[mt][nt] = __builtin_amdgcn_mfma_f32_16x16x32_bf16(bv[nt], av[mt], acc[mt][nt], 0, 0, 0);
    }

#pragma unroll
    for (int mt = 0; mt < 8; ++mt) {
        const int row = by * 256 + wr * 128 + mt * 16 + ln;
#pragma unroll
        for (int nt = 0; nt < 4; ++nt) {
            const int colb = bx * 256 + wc * 64 + nt * 16 + kg * 4;
            const f32x4 a = acc[mt][nt];   // a[r] -> col colb+r
            const float4 b4 = *(const float4*)(bias + colb);
            if constexpr (EPI == 0) {
                bf16_t* o = (bf16_t*)outp;
                bf16x4 ov;
                ov[0] = (bf16_t)(a[0] + b4.x); ov[1] = (bf16_t)(a[1] + b4.y);
                ov[2] = (bf16_t)(a[2] + b4.z); ov[3] = (bf16_t)(a[3] + b4.w);
                *(bf16x4*)(o + (size_t)row * N + colb) = ov;
            } else if constexpr (EPI == 1) {
                const float4 l4 = *(const float4*)(ls + colb);
                float* o = (float*)outp;
                int g = map_p_to_g(row);
                size_t idx = (size_t)g * 256 + colb;
                float4 xr = *(const float4*)(xres + idx);
                float4 r4;
                r4.x = xr.x + l4.x * (a[0] + b4.x);
                r4.y = xr.y + l4.y * (a[1] + b4.y);
                r4.z = xr.z + l4.z * (a[2] + b4.z);
                r4.w = xr.w + l4.w * (a[3] + b4.w);
                *(float4*)(o + idx) = r4;
            } else if constexpr (EPI == 2) {
                bf16_t* o = (bf16_t*)outp;
                bf16x4 ov;
#pragma unroll
                for (int r = 0; r < 4; ++r) {
                    float u2 = a[r] + ((const float*)&b4)[r];
                    // GELU ~= u*sigmoid(1.702u); err ~0.02 ~ bf16 rounding of h1,
                    // x1e-5 downstream -> ~1e-7 at output. NaN-safe at +-inf.
                    float gl = u2 / (1.f + __expf(-1.702f * u2));
                    ov[r] = (bf16_t)gl;
                }
                *(bf16x4*)(o + (size_t)row * N + colb) = ov;
            } else {
                const float4 l4 = *(const float4*)(ls + colb);
                float* o = (float*)outp;
                size_t idx = (size_t)row * 256 + colb;
                float4 cur = *(const float4*)(o + idx);
                cur.x += l4.x * (a[0] + b4.x);
                cur.y += l4.y * (a[1] + b4.y);
                cur.z += l4.z * (a[2] + b4.z);
                cur.w += l4.w * (a[3] + b4.w);
                *(float4*)(o + idx) = cur;
            }
        }
    }
}

__global__ __launch_bounds__(512) void gq_k(const bf16_t* A, const bf16_t* Bt, const float* bias,
                                            void* outp, int N, int K)
{ gemm_body<0, 3>(A, Bt, bias, nullptr, nullptr, outp, N, K); }

__global__ __launch_bounds__(512) void gp_k(const bf16_t* A, const bf16_t* Bt, const float* bias,
                                            const float* xres, const float* ls, void* outp, int N, int K)
{ gemm_body<1, 1>(A, Bt, bias, xres, ls, outp, N, K); }

__global__ __launch_bounds__(512) void g1_k(const bf16_t* A, const bf16_t* Bt, const float* bias,
                                            void* outp, int N, int K)
{ gemm_body<2, 4>(A, Bt, bias, nullptr, nullptr, outp, N, K); }

__global__ __launch_bounds__(512) void g2_k(const bf16_t* A, const bf16_t* Bt, const float* bias,
                                            const float* ls, void* outp, int N, int K)
{ gemm_body<3, 1>(A, Bt, bias, nullptr, ls, outp, N, K); }

// ---------------- fused per-window attention (plain qkv in, plain attno out) ----------------
__global__ __launch_bounds__(256) void attn_k(const bf16_t* __restrict__ qkv,
                                              bf16_t* __restrict__ out)
{
    __shared__ bf16_t Plds[4 * 7040];
    const int t = threadIdx.x, wid = t >> 6, lane = t & 63;
    const int ln = lane & 15, kg = lane >> 4;
    bf16_t* P = &Plds[wid * 7040];
    const int w = blockIdx.x;
    const bf16_t* base = qkv + (size_t)w * 80 * 768;
    const float SCALE = 0.17677669529663689f;

    for (int hh = 0; hh < 2; ++hh) {
        const int h = wid + hh * 4;
        const bf16_t* hb = base + h * 96;
        bf16x8 qa[5], kb[5];
#pragma unroll
        for (int mt = 0; mt < 5; ++mt)
            qa[mt] = *(const bf16x8*)(hb + (size_t)(mt * 16 + ln) * 768 + kg * 8);
#pragma unroll
        for (int nt = 0; nt < 5; ++nt)
            kb[nt] = *(const bf16x8*)(hb + (size_t)(nt * 16 + ln) * 768 + 32 + kg * 8);
        f32x4 S[5][5];
#pragma unroll
        for (int mt = 0; mt < 5; ++mt)
#pragma unroll
            for (int nt = 0; nt < 5; ++nt) {
                f32x4 z = {0.f, 0.f, 0.f, 0.f};
                S[mt][nt] = __builtin_amdgcn_mfma_f32_16x16x32_bf16(qa[mt], kb[nt], z, 0, 0, 0);
            }
#pragma unroll
        for (int mt = 0; mt < 5; ++mt) {
#pragma unroll
            for (int r = 0; r < 4; ++r) {
                float mx = S[mt][0][r];
#pragma unroll
                for (int nt = 1; nt < 5; ++nt) mx = fmaxf(mx, S[mt][nt][r]);
                mx = fmaxf(mx, __shfl_xor(mx, 1, 64));
                mx = fmaxf(mx, __shfl_xor(mx, 2, 64));
                mx = fmaxf(mx, __shfl_xor(mx, 4, 64));
                mx = fmaxf(mx, __shfl_xor(mx, 8, 64));
                float sum = 0.f;
#pragma unroll
                for (int nt = 0; nt < 5; ++nt) {
                    float e = __expf((S[mt][nt][r] - mx) * SCALE);
                    S[mt][nt][r] = e;
                    sum += e;
                }
                sum += __shfl_xor(sum, 1, 64);
                sum += __shfl_xor(sum, 2, 64);
                sum += __shfl_xor(sum, 4, 64);
                sum += __shfl_xor(sum, 8, 64);
                float inv = 1.f / sum;
#pragma unroll
                for (int nt = 0; nt < 5; ++nt) S[mt][nt][r] *= inv;
            }
        }
#pragma unroll
        for (int mt = 0; mt < 5; ++mt)
#pragma unroll
            for (int nt = 0; nt < 5; ++nt)
#pragma unroll
                for (int r = 0; r < 4; ++r)
                    P[(mt * 16 + kg * 4 + r) * 88 + nt * 16 + ln] = (bf16_t)S[mt][nt][r];
        f32x4 O[5][2];
#pragma unroll
        for (int mt = 0; mt < 5; ++mt) {
            O[mt][0] = (f32x4){0.f, 0.f, 0.f, 0.f};
            O[mt][1] = (f32x4){0.f, 0.f, 0.f, 0.f};
        }
#pragma unroll
        for (int nt2 = 0; nt2 < 2; ++nt2) {
#pragma unroll
            for (int kt = 0; kt < 3; ++kt) {
                const bool dead = (kt == 2) && (kg >= 2);
                bf16x8 bv;
#pragma unroll
                for (int j = 0; j < 8; ++j) {
                    int tok = kt * 32 + kg * 8 + j;
                    if (tok > 79) tok = 79;
                    bv[j] = hb[(size_t)tok * 768 + 64 + nt2 * 16 + ln];
                }
                if (dead) {
#pragma unroll
                    for (int j = 0; j < 8; ++j) bv[j] = (bf16_t)0.f;
                }
                int cb = kt * 32 + kg * 8;
                if (cb >= 80) cb = 0;
#pragma unroll
                for (int mt = 0; mt < 5; ++mt) {
                    bf16x8 av = *(const bf16x8*)(P + (mt * 16 + ln) * 88 + cb);
                    O[mt][nt2] = __builtin_amdgcn_mfma_f32_16x16x32_bf16(av, bv, O[mt][nt2], 0, 0, 0);
                }
            }
        }
#pragma unroll
        for (int mt = 0; mt < 5; ++mt)
#pragma unroll
            for (int nt2 = 0; nt2 < 2; ++nt2)
#pragma unroll
                for (int r = 0; r < 4; ++r) {
                    int n = mt * 16 + kg * 4 + r;
                    out[((size_t)w * 80 + n) * 256 + h * 32 + nt2 * 16 + ln] = (bf16_t)O[mt][nt2][r];
                }
    }
}

// ---------------- launch ----------------
extern "C" void kernel_launch(void* const* d_in, const int* in_sizes, int n_in,
                              void* d_out, int out_size, void* d_ws, size_t ws_size,
                              hipStream_t stream)
{
    (void)in_sizes; (void)n_in; (void)out_size; (void)ws_size;
    const float* x     = (const float*)d_in[0];
    const float* n1g   = (const float*)d_in[1];
    const float* n1b   = (const float*)d_in[2];
    const float* qkvw  = (const float*)d_in[3];
    const float* qkvb  = (const float*)d_in[4];
    const float* projw = (const float*)d_in[5];
    const float* projb = (const float*)d_in[6];
    const float* ls1   = (const float*)d_in[7];
    const float* n2g   = (const float*)d_in[8];
    const float* n2b   = (const float*)d_in[9];
    const float* fc1w  = (const float*)d_in[10];
    const float* fc1b  = (const float*)d_in[11];
    const float* fc2w  = (const float*)d_in[12];
    const float* fc2b  = (const float*)d_in[13];
    const float* ls2   = (const float*)d_in[14];
    float* out = (float*)d_out;

    // ws (bytes): [0,42MB) actA: ln1p -> attno -> ln2 (sequential reuse)
    //             [42,210MB) big: qkv plain 126MB -> h1 plain 168MB (sequential reuse)
    //             [210MB,..) transposed bf16 weights ~1.5MB
    char* ws = (char*)d_ws;
    bf16_t* actA   = (bf16_t*)(ws);
    bf16_t* qkv    = (bf16_t*)(ws + 41943040ull);
    bf16_t* h1     = (bf16_t*)(ws + 41943040ull);
    bf16_t* wbuf   = (bf16_t*)(ws + 209715200ull);
    bf16_t* qkvwt  = wbuf;                          // [768][256]
    bf16_t* projwt = qkvwt + 768 * 256;             // [256][256]
    bf16_t* fc1wt  = projwt + 256 * 256;            // [1024][256]
    bf16_t* fc2wt  = fc1wt + 1024 * 256;            // [256][1024]

    wconv_k<<<768,  256, 0, stream>>>(qkvw,  qkvwt, 768, 256);
    wconv_k<<<256,  256, 0, stream>>>(projw, projwt, 256, 256);
    wconv_k<<<1024, 256, 0, stream>>>(fc1w,  fc1wt, 1024, 256);
    wconv_k<<<1024, 256, 0, stream>>>(fc2w,  fc2wt, 256, 1024);

    ln_k<1><<<20480, 256, 0, stream>>>(x, n1g, n1b, actA);
    gq_k<<<960, 512, 0, stream>>>(actA, qkvwt, qkvb, qkv, 768, 256);          // 320x3 blocks
    attn_k<<<1024, 256, 0, stream>>>(qkv, actA);
    gp_k<<<320, 512, 0, stream>>>(actA, projwt, projb, x, ls1, out, 256, 256);
    ln_k<0><<<20480, 256, 0, stream>>>(out, n2g, n2b, actA);
    g1_k<<<1280, 512, 0, stream>>>(actA, fc1wt, fc1b, h1, 1024, 256);         // 320x4 blocks
    g2_k<<<320, 512, 0, stream>>>(h1, fc2wt, fc2b, ls2, out, 256, 1024);
}

// Round 13
// 445.515 us; speedup vs baseline: 1.2213x; 1.2213x over previous
//
#include <hip/hip_runtime.h>
#include <hip/hip_bf16.h>
#include <stdint.h>
#include <math.h>

typedef __bf16 bf16_t;
typedef __bf16 bf16x8 __attribute__((ext_vector_type(8)));
typedef __bf16 bf16x4 __attribute__((ext_vector_type(4)));
typedef float  f32x4  __attribute__((ext_vector_type(4)));

typedef __attribute__((address_space(1))) const void global_cv;
typedef __attribute__((address_space(3))) void lds_v;

// Problem constants: B=16,H=64,W=80,C=256; GH=8,GW=10; heads=8,DH=32; INNER=1024

__device__ __forceinline__ int map_p_to_g(int p) {
    int w = p / 80, n = p - w * 80;
    int b  = w >> 6, h2 = (w >> 3) & 7, w2 = w & 7;
    int gh = n / 10, gw = n - gh * 10;
    return b * 5120 + (gh * 8 + h2) * 80 + (gw * 8 + w2);
}

// XOR swizzle for 128-B LDS rows: bits 4-6 ^= bits 7-9 (involution, keeps 16B align)
__device__ __forceinline__ int swz128(int b) { return b ^ (((b >> 7) & 7) << 4); }

// ---------------- weight convert+transpose: fp32 [K][N] -> bf16 [N][K] ----------------
__global__ __launch_bounds__(256) void wconv_k(const float* __restrict__ in,
                                               bf16_t* __restrict__ out, int N, int K)
{
    int i = blockIdx.x * 256 + threadIdx.x;
    int n = i / K, k = i - n * K;
    out[i] = (bf16_t)in[(size_t)k * N + n];
}

// ---------------- LayerNorm (one wave per row), optional partition permute ----------------
template <int PERM>
__global__ __launch_bounds__(256) void ln_k(const float* __restrict__ in,
                                            const float* __restrict__ gg,
                                            const float* __restrict__ bb,
                                            bf16_t* __restrict__ o)
{
    int row  = blockIdx.x * 4 + (threadIdx.x >> 6);
    int lane = threadIdx.x & 63;
    const float4 xv = *(const float4*)(in + (size_t)row * 256 + lane * 4);
    float s = xv.x + xv.y + xv.z + xv.w;
#pragma unroll
    for (int m = 1; m < 64; m <<= 1) s += __shfl_xor(s, m, 64);
    float mean = s * (1.f / 256.f);
    float d0 = xv.x - mean, d1 = xv.y - mean, d2 = xv.z - mean, d3 = xv.w - mean;
    float v = d0 * d0 + d1 * d1 + d2 * d2 + d3 * d3;
#pragma unroll
    for (int m = 1; m < 64; m <<= 1) v += __shfl_xor(v, m, 64);
    float rstd = rsqrtf(v * (1.f / 256.f) + 1e-5f);
    const float4 gv = *(const float4*)(gg + lane * 4);
    const float4 bv = *(const float4*)(bb + lane * 4);
    int orow = row;
    if (PERM) {
        int b = row / 5120, r1 = row - b * 5120;
        int h = r1 / 80, wv = r1 - h * 80;
        int gh = h >> 3, h2 = h & 7, gw = wv >> 3, w2 = wv & 7;
        orow = ((b * 8 + h2) * 8 + w2) * 80 + gh * 10 + gw;
    }
    bf16x4 ov;
    ov[0] = (bf16_t)(d0 * rstd * gv.x + bv.x);
    ov[1] = (bf16_t)(d1 * rstd * gv.y + bv.y);
    ov[2] = (bf16_t)(d2 * rstd * gv.z + bv.z);
    ov[3] = (bf16_t)(d3 * rstd * gv.w + bv.w);
    *(bf16x4*)(o + (size_t)orow * 256 + lane * 4) = ov;
}

// ---------------- 128x128-tile MFMA GEMM, high-occupancy (4 blocks/CU target) ----------------
// Single 32-KB LDS buffer, BK=64, 4 waves (2x2, 64x64 each). r2-proven gload_lds staging
// with both-sides swz128 (rule 21); XCD-bijective 1D grid (r7); swapped mfma operands
// (bv,av) -> D^T: our row = ln, our cols = kg*4+r -> vectorized epilogue (r11).
// Cross-block wave overlap (4 blocks/CU) hides the per-step stage drain (m114).
// EPI 0: bf16 out (+bias) [qkv]; 1: fp32 x[g]+ls*(acc+b), grid-reverse [proj];
// EPI 2: bf16 gelu_sig    [fc1]; 3: fp32 out += ls*(acc+b) [fc2]
template <int EPI, int NBX>
__device__ __forceinline__ void gemm_body(const bf16_t* __restrict__ A,
                                          const bf16_t* __restrict__ Bt,
                                          const float* __restrict__ bias,
                                          const float* __restrict__ xres,
                                          const float* __restrict__ ls,
                                          void* __restrict__ outp,
                                          int N, int K)
{
    __shared__ bf16_t At[128 * 64];   // 16 KB: 128 rows x 128 B, swizzled content
    __shared__ bf16_t Bl[128 * 64];
    const int t = threadIdx.x;
    const int wid = t >> 6, lane = t & 63;
    const int wr = wid >> 1, wc = wid & 1;
    const int ln = lane & 15, kg = lane >> 4;

    // bijective XCD swizzle: grid = NBY*NBX, NBY multiple of 8
    const int f   = blockIdx.x;
    const int xcd = f & 7, jj = f >> 3;
    const int byx = (gridDim.x >> 3) / NBX;
    const int by  = xcd * byx + jj / NBX;
    const int bx  = jj % NBX;

    const size_t Kb = (size_t)K * 2;
    const char* Ab = (const char*)(A  + (size_t)by * 128 * K);
    const char* Bb = (const char*)(Bt + (size_t)bx * 128 * K);
    char* AtB = (char*)At;
    char* BlB = (char*)Bl;

    const f32x4 fz = {0.f, 0.f, 0.f, 0.f};
    f32x4 acc[4][4];
#pragma unroll
    for (int i = 0; i < 4; ++i)
#pragma unroll
        for (int j = 0; j < 4; ++j) acc[i][j] = fz;

    const int nsteps = K >> 6;

    for (int s = 0; s < nsteps; ++s) {
        const size_t kb = (size_t)s * 128;
#pragma unroll
        for (int i = 0; i < 4; ++i) {
            int p   = (i * 256 + t) * 16;
            int row = p >> 7;
            int off = (p & 127) ^ ((row & 7) << 4);   // inverse-swizzled source
            __builtin_amdgcn_global_load_lds((global_cv*)(Ab + (size_t)row * Kb + kb + off),
                                             (lds_v*)(AtB + p), 16, 0, 0);
            __builtin_amdgcn_global_load_lds((global_cv*)(Bb + (size_t)row * Kb + kb + off),
                                             (lds_v*)(BlB + p), 16, 0, 0);
        }
        __syncthreads();   // drains stage; other resident blocks cover the gap
#pragma unroll
        for (int kk = 0; kk < 2; ++kk) {
            bf16x8 av[4], bv[4];
#pragma unroll
            for (int mt = 0; mt < 4; ++mt) {
                int row = wr * 64 + mt * 16 + ln;
                av[mt] = *(const bf16x8*)(AtB + swz128(row * 128 + kk * 64 + kg * 16));
            }
#pragma unroll
            for (int nt = 0; nt < 4; ++nt) {
                int row = wc * 64 + nt * 16 + ln;
                bv[nt] = *(const bf16x8*)(BlB + swz128(row * 128 + kk * 64 + kg * 16));
            }
            // swapped operands: D^T layout -> our row=ln, our cols=kg*4+r
#pragma unroll
            for (int mt = 0; mt < 4; ++mt)
#pragma unroll
                for (int nt = 0; nt < 4; ++nt)
                    acc[mt][nt] = __builtin_amdgcn_mfma_f32_16x16x32_bf16(bv[nt], av[mt], acc[mt][nt], 0, 0, 0);
        }
        __syncthreads();   // protect LDS before next stage
    }

#pragma unroll
    for (int mt = 0; mt < 4; ++mt) {
        const int row = by * 128 + wr * 64 + mt * 16 + ln;
#pragma unroll
        for (int nt = 0; nt < 4; ++nt) {
            const int colb = bx * 128 + wc * 64 + nt * 16 + kg * 4;
            const f32x4 a = acc[mt][nt];   // a[r] -> col colb+r
            const float4 b4 = *(const float4*)(bias + colb);
            if constexpr (EPI == 0) {
                bf16_t* o = (bf16_t*)outp;
                bf16x4 ov;
                ov[0] = (bf16_t)(a[0] + b4.x); ov[1] = (bf16_t)(a[1] + b4.y);
                ov[2] = (bf16_t)(a[2] + b4.z); ov[3] = (bf16_t)(a[3] + b4.w);
                *(bf16x4*)(o + (size_t)row * N + colb) = ov;
            } else if constexpr (EPI == 1) {
                const float4 l4 = *(const float4*)(ls + colb);
                float* o = (float*)outp;
                int g = map_p_to_g(row);
                size_t idx = (size_t)g * 256 + colb;
                float4 xr = *(const float4*)(xres + idx);
                float4 r4;
                r4.x = xr.x + l4.x * (a[0] + b4.x);
                r4.y = xr.y + l4.y * (a[1] + b4.y);
                r4.z = xr.z + l4.z * (a[2] + b4.z);
                r4.w = xr.w + l4.w * (a[3] + b4.w);
                *(float4*)(o + idx) = r4;
            } else if constexpr (EPI == 2) {
                bf16_t* o = (bf16_t*)outp;
                bf16x4 ov;
#pragma unroll
                for (int r = 0; r < 4; ++r) {
                    float u2 = a[r] + ((const float*)&b4)[r];
                    // GELU ~= u*sigmoid(1.702u); err ~0.02 ~ bf16 rounding of h1,
                    // x1e-5 downstream -> ~1e-7 at output. NaN-safe at +-inf.
                    float gl = u2 / (1.f + __expf(-1.702f * u2));
                    ov[r] = (bf16_t)gl;
                }
                *(bf16x4*)(o + (size_t)row * N + colb) = ov;
            } else {
                const float4 l4 = *(const float4*)(ls + colb);
                float* o = (float*)outp;
                size_t idx = (size_t)row * 256 + colb;
                float4 cur = *(const float4*)(o + idx);
                cur.x += l4.x * (a[0] + b4.x);
                cur.y += l4.y * (a[1] + b4.y);
                cur.z += l4.z * (a[2] + b4.z);
                cur.w += l4.w * (a[3] + b4.w);
                *(float4*)(o + idx) = cur;
            }
        }
    }
}

__global__ __launch_bounds__(256, 4) void gq_k(const bf16_t* A, const bf16_t* Bt, const float* bias,
                                               void* outp, int N, int K)
{ gemm_body<0, 6>(A, Bt, bias, nullptr, nullptr, outp, N, K); }

__global__ __launch_bounds__(256, 4) void gp_k(const bf16_t* A, const bf16_t* Bt, const float* bias,
                                               const float* xres, const float* ls, void* outp, int N, int K)
{ gemm_body<1, 2>(A, Bt, bias, xres, ls, outp, N, K); }

__global__ __launch_bounds__(256, 4) void g1_k(const bf16_t* A, const bf16_t* Bt, const float* bias,
                                               void* outp, int N, int K)
{ gemm_body<2, 8>(A, Bt, bias, nullptr, nullptr, outp, N, K); }

__global__ __launch_bounds__(256, 4) void g2_k(const bf16_t* A, const bf16_t* Bt, const float* bias,
                                               const float* ls, void* outp, int N, int K)
{ gemm_body<3, 2>(A, Bt, bias, nullptr, ls, outp, N, K); }

// ---------------- fused per-window attention (plain qkv in, plain attno out) ----------------
__global__ __launch_bounds__(256) void attn_k(const bf16_t* __restrict__ qkv,
                                              bf16_t* __restrict__ out)
{
    __shared__ bf16_t Plds[4 * 7040];
    const int t = threadIdx.x, wid = t >> 6, lane = t & 63;
    const int ln = lane & 15, kg = lane >> 4;
    bf16_t* P = &Plds[wid * 7040];
    const int w = blockIdx.x;
    const bf16_t* base = qkv + (size_t)w * 80 * 768;
    const float SCALE = 0.17677669529663689f;

    for (int hh = 0; hh < 2; ++hh) {
        const int h = wid + hh * 4;
        const bf16_t* hb = base + h * 96;
        bf16x8 qa[5], kb[5];
#pragma unroll
        for (int mt = 0; mt < 5; ++mt)
            qa[mt] = *(const bf16x8*)(hb + (size_t)(mt * 16 + ln) * 768 + kg * 8);
#pragma unroll
        for (int nt = 0; nt < 5; ++nt)
            kb[nt] = *(const bf16x8*)(hb + (size_t)(nt * 16 + ln) * 768 + 32 + kg * 8);
        f32x4 S[5][5];
#pragma unroll
        for (int mt = 0; mt < 5; ++mt)
#pragma unroll
            for (int nt = 0; nt < 5; ++nt) {
                f32x4 z = {0.f, 0.f, 0.f, 0.f};
                S[mt][nt] = __builtin_amdgcn_mfma_f32_16x16x32_bf16(qa[mt], kb[nt], z, 0, 0, 0);
            }
#pragma unroll
        for (int mt = 0; mt < 5; ++mt) {
#pragma unroll
            for (int r = 0; r < 4; ++r) {
                float mx = S[mt][0][r];
#pragma unroll
                for (int nt = 1; nt < 5; ++nt) mx = fmaxf(mx, S[mt][nt][r]);
                mx = fmaxf(mx, __shfl_xor(mx, 1, 64));
                mx = fmaxf(mx, __shfl_xor(mx, 2, 64));
                mx = fmaxf(mx, __shfl_xor(mx, 4, 64));
                mx = fmaxf(mx, __shfl_xor(mx, 8, 64));
                float sum = 0.f;
#pragma unroll
                for (int nt = 0; nt < 5; ++nt) {
                    float e = __expf((S[mt][nt][r] - mx) * SCALE);
                    S[mt][nt][r] = e;
                    sum += e;
                }
                sum += __shfl_xor(sum, 1, 64);
                sum += __shfl_xor(sum, 2, 64);
                sum += __shfl_xor(sum, 4, 64);
                sum += __shfl_xor(sum, 8, 64);
                float inv = 1.f / sum;
#pragma unroll
                for (int nt = 0; nt < 5; ++nt) S[mt][nt][r] *= inv;
            }
        }
#pragma unroll
        for (int mt = 0; mt < 5; ++mt)
#pragma unroll
            for (int nt = 0; nt < 5; ++nt)
#pragma unroll
                for (int r = 0; r < 4; ++r)
                    P[(mt * 16 + kg * 4 + r) * 88 + nt * 16 + ln] = (bf16_t)S[mt][nt][r];
        f32x4 O[5][2];
#pragma unroll
        for (int mt = 0; mt < 5; ++mt) {
            O[mt][0] = (f32x4){0.f, 0.f, 0.f, 0.f};
            O[mt][1] = (f32x4){0.f, 0.f, 0.f, 0.f};
        }
#pragma unroll
        for (int nt2 = 0; nt2 < 2; ++nt2) {
#pragma unroll
            for (int kt = 0; kt < 3; ++kt) {
                const bool dead = (kt == 2) && (kg >= 2);
                bf16x8 bv;
#pragma unroll
                for (int j = 0; j < 8; ++j) {
                    int tok = kt * 32 + kg * 8 + j;
                    if (tok > 79) tok = 79;
                    bv[j] = hb[(size_t)tok * 768 + 64 + nt2 * 16 + ln];
                }
                if (dead) {
#pragma unroll
                    for (int j = 0; j < 8; ++j) bv[j] = (bf16_t)0.f;
                }
                int cb = kt * 32 + kg * 8;
                if (cb >= 80) cb = 0;
#pragma unroll
                for (int mt = 0; mt < 5; ++mt) {
                    bf16x8 av = *(const bf16x8*)(P + (mt * 16 + ln) * 88 + cb);
                    O[mt][nt2] = __builtin_amdgcn_mfma_f32_16x16x32_bf16(av, bv, O[mt][nt2], 0, 0, 0);
                }
            }
        }
#pragma unroll
        for (int mt = 0; mt < 5; ++mt)
#pragma unroll
            for (int nt2 = 0; nt2 < 2; ++nt2)
#pragma unroll
                for (int r = 0; r < 4; ++r) {
                    int n = mt * 16 + kg * 4 + r;
                    out[((size_t)w * 80 + n) * 256 + h * 32 + nt2 * 16 + ln] = (bf16_t)O[mt][nt2][r];
                }
    }
}

// ---------------- launch ----------------
extern "C" void kernel_launch(void* const* d_in, const int* in_sizes, int n_in,
                              void* d_out, int out_size, void* d_ws, size_t ws_size,
                              hipStream_t stream)
{
    (void)in_sizes; (void)n_in; (void)out_size; (void)ws_size;
    const float* x     = (const float*)d_in[0];
    const float* n1g   = (const float*)d_in[1];
    const float* n1b   = (const float*)d_in[2];
    const float* qkvw  = (const float*)d_in[3];
    const float* qkvb  = (const float*)d_in[4];
    const float* projw = (const float*)d_in[5];
    const float* projb = (const float*)d_in[6];
    const float* ls1   = (const float*)d_in[7];
    const float* n2g   = (const float*)d_in[8];
    const float* n2b   = (const float*)d_in[9];
    const float* fc1w  = (const float*)d_in[10];
    const float* fc1b  = (const float*)d_in[11];
    const float* fc2w  = (const float*)d_in[12];
    const float* fc2b  = (const float*)d_in[13];
    const float* ls2   = (const float*)d_in[14];
    float* out = (float*)d_out;

    // ws (bytes): [0,42MB) actA: ln1p -> attno -> ln2 (sequential reuse)
    //             [42,210MB) big: qkv plain 126MB -> h1 plain 168MB (sequential reuse)
    //             [210MB,..) transposed bf16 weights ~1.5MB
    char* ws = (char*)d_ws;
    bf16_t* actA   = (bf16_t*)(ws);
    bf16_t* qkv    = (bf16_t*)(ws + 41943040ull);
    bf16_t* h1     = (bf16_t*)(ws + 41943040ull);
    bf16_t* wbuf   = (bf16_t*)(ws + 209715200ull);
    bf16_t* qkvwt  = wbuf;                          // [768][256]
    bf16_t* projwt = qkvwt + 768 * 256;             // [256][256]
    bf16_t* fc1wt  = projwt + 256 * 256;            // [1024][256]
    bf16_t* fc2wt  = fc1wt + 1024 * 256;            // [256][1024]

    wconv_k<<<768,  256, 0, stream>>>(qkvw,  qkvwt, 768, 256);
    wconv_k<<<256,  256, 0, stream>>>(projw, projwt, 256, 256);
    wconv_k<<<1024, 256, 0, stream>>>(fc1w,  fc1wt, 1024, 256);
    wconv_k<<<1024, 256, 0, stream>>>(fc2w,  fc2wt, 256, 1024);

    ln_k<1><<<20480, 256, 0, stream>>>(x, n1g, n1b, actA);
    gq_k<<<3840, 256, 0, stream>>>(actA, qkvwt, qkvb, qkv, 768, 256);   // 640 x 6
    attn_k<<<1024, 256, 0, stream>>>(qkv, actA);
    gp_k<<<1280, 256, 0, stream>>>(actA, projwt, projb, x, ls1, out, 256, 256);   // 640 x 2
    ln_k<0><<<20480, 256, 0, stream>>>(out, n2g, n2b, actA);
    g1_k<<<5120, 256, 0, stream>>>(actA, fc1wt, fc1b, h1, 1024, 256);   // 640 x 8
    g2_k<<<1280, 256, 0, stream>>>(h1, fc2wt, fc2b, ls2, out, 256, 1024);   // 640 x 2
}

// Round 14
// 405.141 us; speedup vs baseline: 1.3430x; 1.0997x over previous
//
#include <hip/hip_runtime.h>
#include <hip/hip_bf16.h>
#include <stdint.h>
#include <math.h>

typedef __bf16 bf16_t;
typedef __bf16 bf16x8 __attribute__((ext_vector_type(8)));
typedef __bf16 bf16x4 __attribute__((ext_vector_type(4)));
typedef float  f32x4  __attribute__((ext_vector_type(4)));

typedef __attribute__((address_space(1))) const void global_cv;
typedef __attribute__((address_space(3))) void lds_v;

// Problem constants: B=16,H=64,W=80,C=256; GH=8,GW=10; heads=8,DH=32; INNER=1024

__device__ __forceinline__ int map_p_to_g(int p) {
    int w = p / 80, n = p - w * 80;
    int b  = w >> 6, h2 = (w >> 3) & 7, w2 = w & 7;
    int gh = n / 10, gw = n - gh * 10;
    return b * 5120 + (gh * 8 + h2) * 80 + (gw * 8 + w2);
}

// XOR swizzle for 128-B LDS rows: bits 4-6 ^= bits 7-9 (involution, keeps 16B align)
__device__ __forceinline__ int swz128(int b) { return b ^ (((b >> 7) & 7) << 4); }

// ---------------- weight convert+transpose: fp32 [K][N] -> bf16 [N][K] ----------------
__global__ __launch_bounds__(256) void wconv_k(const float* __restrict__ in,
                                               bf16_t* __restrict__ out, int N, int K)
{
    int i = blockIdx.x * 256 + threadIdx.x;
    int n = i / K, k = i - n * K;
    out[i] = (bf16_t)in[(size_t)k * N + n];
}

// ---------------- LayerNorm (one wave per row), optional partition permute ----------------
template <int PERM>
__global__ __launch_bounds__(256) void ln_k(const float* __restrict__ in,
                                            const float* __restrict__ gg,
                                            const float* __restrict__ bb,
                                            bf16_t* __restrict__ o)
{
    int row  = blockIdx.x * 4 + (threadIdx.x >> 6);
    int lane = threadIdx.x & 63;
    const float4 xv = *(const float4*)(in + (size_t)row * 256 + lane * 4);
    float s = xv.x + xv.y + xv.z + xv.w;
#pragma unroll
    for (int m = 1; m < 64; m <<= 1) s += __shfl_xor(s, m, 64);
    float mean = s * (1.f / 256.f);
    float d0 = xv.x - mean, d1 = xv.y - mean, d2 = xv.z - mean, d3 = xv.w - mean;
    float v = d0 * d0 + d1 * d1 + d2 * d2 + d3 * d3;
#pragma unroll
    for (int m = 1; m < 64; m <<= 1) v += __shfl_xor(v, m, 64);
    float rstd = rsqrtf(v * (1.f / 256.f) + 1e-5f);
    const float4 gv = *(const float4*)(gg + lane * 4);
    const float4 bv = *(const float4*)(bb + lane * 4);
    int orow = row;
    if (PERM) {
        int b = row / 5120, r1 = row - b * 5120;
        int h = r1 / 80, wv = r1 - h * 80;
        int gh = h >> 3, h2 = h & 7, gw = wv >> 3, w2 = wv & 7;
        orow = ((b * 8 + h2) * 8 + w2) * 80 + gh * 10 + gw;
    }
    bf16x4 ov;
    ov[0] = (bf16_t)(d0 * rstd * gv.x + bv.x);
    ov[1] = (bf16_t)(d1 * rstd * gv.y + bv.y);
    ov[2] = (bf16_t)(d2 * rstd * gv.z + bv.z);
    ov[3] = (bf16_t)(d3 * rstd * gv.w + bv.w);
    *(bf16x4*)(o + (size_t)orow * 256 + lane * 4) = ov;
}

// ---------------- 128x128-tile MFMA GEMM, high-occupancy (r13, unchanged) ----------------
template <int EPI, int NBX>
__device__ __forceinline__ void gemm_body(const bf16_t* __restrict__ A,
                                          const bf16_t* __restrict__ Bt,
                                          const float* __restrict__ bias,
                                          const float* __restrict__ xres,
                                          const float* __restrict__ ls,
                                          void* __restrict__ outp,
                                          int N, int K)
{
    __shared__ bf16_t At[128 * 64];   // 16 KB: 128 rows x 128 B, swizzled content
    __shared__ bf16_t Bl[128 * 64];
    const int t = threadIdx.x;
    const int wid = t >> 6, lane = t & 63;
    const int wr = wid >> 1, wc = wid & 1;
    const int ln = lane & 15, kg = lane >> 4;

    const int f   = blockIdx.x;
    const int xcd = f & 7, jj = f >> 3;
    const int byx = (gridDim.x >> 3) / NBX;
    const int by  = xcd * byx + jj / NBX;
    const int bx  = jj % NBX;

    const size_t Kb = (size_t)K * 2;
    const char* Ab = (const char*)(A  + (size_t)by * 128 * K);
    const char* Bb = (const char*)(Bt + (size_t)bx * 128 * K);
    char* AtB = (char*)At;
    char* BlB = (char*)Bl;

    const f32x4 fz = {0.f, 0.f, 0.f, 0.f};
    f32x4 acc[4][4];
#pragma unroll
    for (int i = 0; i < 4; ++i)
#pragma unroll
        for (int j = 0; j < 4; ++j) acc[i][j] = fz;

    const int nsteps = K >> 6;

    for (int s = 0; s < nsteps; ++s) {
        const size_t kb = (size_t)s * 128;
#pragma unroll
        for (int i = 0; i < 4; ++i) {
            int p   = (i * 256 + t) * 16;
            int row = p >> 7;
            int off = (p & 127) ^ ((row & 7) << 4);   // inverse-swizzled source
            __builtin_amdgcn_global_load_lds((global_cv*)(Ab + (size_t)row * Kb + kb + off),
                                             (lds_v*)(AtB + p), 16, 0, 0);
            __builtin_amdgcn_global_load_lds((global_cv*)(Bb + (size_t)row * Kb + kb + off),
                                             (lds_v*)(BlB + p), 16, 0, 0);
        }
        __syncthreads();
#pragma unroll
        for (int kk = 0; kk < 2; ++kk) {
            bf16x8 av[4], bv[4];
#pragma unroll
            for (int mt = 0; mt < 4; ++mt) {
                int row = wr * 64 + mt * 16 + ln;
                av[mt] = *(const bf16x8*)(AtB + swz128(row * 128 + kk * 64 + kg * 16));
            }
#pragma unroll
            for (int nt = 0; nt < 4; ++nt) {
                int row = wc * 64 + nt * 16 + ln;
                bv[nt] = *(const bf16x8*)(BlB + swz128(row * 128 + kk * 64 + kg * 16));
            }
            // swapped operands: D^T layout -> our row=ln, our cols=kg*4+r
#pragma unroll
            for (int mt = 0; mt < 4; ++mt)
#pragma unroll
                for (int nt = 0; nt < 4; ++nt)
                    acc[mt][nt] = __builtin_amdgcn_mfma_f32_16x16x32_bf16(bv[nt], av[mt], acc[mt][nt], 0, 0, 0);
        }
        __syncthreads();
    }

#pragma unroll
    for (int mt = 0; mt < 4; ++mt) {
        const int row = by * 128 + wr * 64 + mt * 16 + ln;
#pragma unroll
        for (int nt = 0; nt < 4; ++nt) {
            const int colb = bx * 128 + wc * 64 + nt * 16 + kg * 4;
            const f32x4 a = acc[mt][nt];   // a[r] -> col colb+r
            const float4 b4 = *(const float4*)(bias + colb);
            if constexpr (EPI == 0) {
                bf16_t* o = (bf16_t*)outp;
                bf16x4 ov;
                ov[0] = (bf16_t)(a[0] + b4.x); ov[1] = (bf16_t)(a[1] + b4.y);
                ov[2] = (bf16_t)(a[2] + b4.z); ov[3] = (bf16_t)(a[3] + b4.w);
                *(bf16x4*)(o + (size_t)row * N + colb) = ov;
            } else if constexpr (EPI == 1) {
                const float4 l4 = *(const float4*)(ls + colb);
                float* o = (float*)outp;
                int g = map_p_to_g(row);
                size_t idx = (size_t)g * 256 + colb;
                float4 xr = *(const float4*)(xres + idx);
                float4 r4;
                r4.x = xr.x + l4.x * (a[0] + b4.x);
                r4.y = xr.y + l4.y * (a[1] + b4.y);
                r4.z = xr.z + l4.z * (a[2] + b4.z);
                r4.w = xr.w + l4.w * (a[3] + b4.w);
                *(float4*)(o + idx) = r4;
            } else if constexpr (EPI == 2) {
                bf16_t* o = (bf16_t*)outp;
                bf16x4 ov;
#pragma unroll
                for (int r = 0; r < 4; ++r) {
                    float u2 = a[r] + ((const float*)&b4)[r];
                    // GELU ~= u*sigmoid(1.702u); err ~0.02 ~ bf16 rounding of h1,
                    // x1e-5 downstream -> ~1e-7 at output. NaN-safe at +-inf.
                    float gl = u2 / (1.f + __expf(-1.702f * u2));
                    ov[r] = (bf16_t)gl;
                }
                *(bf16x4*)(o + (size_t)row * N + colb) = ov;
            } else {
                const float4 l4 = *(const float4*)(ls + colb);
                float* o = (float*)outp;
                size_t idx = (size_t)row * 256 + colb;
                float4 cur = *(const float4*)(o + idx);
                cur.x += l4.x * (a[0] + b4.x);
                cur.y += l4.y * (a[1] + b4.y);
                cur.z += l4.z * (a[2] + b4.z);
                cur.w += l4.w * (a[3] + b4.w);
                *(float4*)(o + idx) = cur;
            }
        }
    }
}

__global__ __launch_bounds__(256, 4) void gq_k(const bf16_t* A, const bf16_t* Bt, const float* bias,
                                               void* outp, int N, int K)
{ gemm_body<0, 6>(A, Bt, bias, nullptr, nullptr, outp, N, K); }

__global__ __launch_bounds__(256, 4) void gp_k(const bf16_t* A, const bf16_t* Bt, const float* bias,
                                               const float* xres, const float* ls, void* outp, int N, int K)
{ gemm_body<1, 2>(A, Bt, bias, xres, ls, outp, N, K); }

__global__ __launch_bounds__(256, 4) void g1_k(const bf16_t* A, const bf16_t* Bt, const float* bias,
                                               void* outp, int N, int K)
{ gemm_body<2, 8>(A, Bt, bias, nullptr, nullptr, outp, N, K); }

__global__ __launch_bounds__(256, 4) void g2_k(const bf16_t* A, const bf16_t* Bt, const float* bias,
                                               const float* ls, void* outp, int N, int K)
{ gemm_body<3, 2>(A, Bt, bias, nullptr, ls, outp, N, K); }

// ---------------- fused per-window attention ----------------
// r13 structure + V staged transposed in per-wave LDS (fixes the 96 scalar V loads/lane):
// global side: coalesced bf16x8 row reads; PV B-fragments: single ds_read_b128 from Vt.
// Per-wave LDS: P[80][88] + Vt[32][88] (+pad). No cross-wave sharing -> no barriers.
__global__ __launch_bounds__(256) void attn_k(const bf16_t* __restrict__ qkv,
                                              bf16_t* __restrict__ out)
{
    __shared__ bf16_t Slds[4 * 9888];     // per wave: P 7040 + Vt 2816 + pad 32
    const int t = threadIdx.x, wid = t >> 6, lane = t & 63;
    const int ln = lane & 15, kg = lane >> 4;
    bf16_t* P  = &Slds[wid * 9888];
    bf16_t* Vt = P + 7040;
    const int w = blockIdx.x;
    const bf16_t* base = qkv + (size_t)w * 80 * 768;
    const float SCALE = 0.17677669529663689f;

    for (int hh = 0; hh < 2; ++hh) {
        const int h = wid + hh * 4;
        const bf16_t* hb = base + h * 96;

        // ---- stage V transposed: Vt[d][tok], rows 88 elems (176 B, 16B-aligned)
#pragma unroll
        for (int half = 0; half < 2; ++half) {
            int tok = half * 64 + lane;
            if (tok < 80) {
                const bf16_t* vr = hb + (size_t)tok * 768 + 64;
#pragma unroll
                for (int q8 = 0; q8 < 4; ++q8) {
                    bf16x8 v = *(const bf16x8*)(vr + q8 * 8);
#pragma unroll
                    for (int j = 0; j < 8; ++j)
                        Vt[(q8 * 8 + j) * 88 + tok] = v[j];
                }
            }
        }

        // ---- S = Q K^T
        bf16x8 qa[5], kb[5];
#pragma unroll
        for (int mt = 0; mt < 5; ++mt)
            qa[mt] = *(const bf16x8*)(hb + (size_t)(mt * 16 + ln) * 768 + kg * 8);
#pragma unroll
        for (int nt = 0; nt < 5; ++nt)
            kb[nt] = *(const bf16x8*)(hb + (size_t)(nt * 16 + ln) * 768 + 32 + kg * 8);
        f32x4 S[5][5];
#pragma unroll
        for (int mt = 0; mt < 5; ++mt)
#pragma unroll
            for (int nt = 0; nt < 5; ++nt) {
                f32x4 z = {0.f, 0.f, 0.f, 0.f};
                S[mt][nt] = __builtin_amdgcn_mfma_f32_16x16x32_bf16(qa[mt], kb[nt], z, 0, 0, 0);
            }
        // ---- softmax over rows (row n = mt*16+kg*4+r in 16 lanes x 5 regs)
#pragma unroll
        for (int mt = 0; mt < 5; ++mt) {
#pragma unroll
            for (int r = 0; r < 4; ++r) {
                float mx = S[mt][0][r];
#pragma unroll
                for (int nt = 1; nt < 5; ++nt) mx = fmaxf(mx, S[mt][nt][r]);
                mx = fmaxf(mx, __shfl_xor(mx, 1, 64));
                mx = fmaxf(mx, __shfl_xor(mx, 2, 64));
                mx = fmaxf(mx, __shfl_xor(mx, 4, 64));
                mx = fmaxf(mx, __shfl_xor(mx, 8, 64));
                float sum = 0.f;
#pragma unroll
                for (int nt = 0; nt < 5; ++nt) {
                    float e = __expf((S[mt][nt][r] - mx) * SCALE);
                    S[mt][nt][r] = e;
                    sum += e;
                }
                sum += __shfl_xor(sum, 1, 64);
                sum += __shfl_xor(sum, 2, 64);
                sum += __shfl_xor(sum, 4, 64);
                sum += __shfl_xor(sum, 8, 64);
                float inv = 1.f / sum;
#pragma unroll
                for (int nt = 0; nt < 5; ++nt) S[mt][nt][r] *= inv;
            }
        }
        // ---- P -> LDS (D-layout scatter), consumed as A-operand
#pragma unroll
        for (int mt = 0; mt < 5; ++mt)
#pragma unroll
            for (int nt = 0; nt < 5; ++nt)
#pragma unroll
                for (int r = 0; r < 4; ++r)
                    P[(mt * 16 + kg * 4 + r) * 88 + nt * 16 + ln] = (bf16_t)S[mt][nt][r];
        // ---- O = P V ; V^T fragments now 16-B ds_reads from Vt
        f32x4 O[5][2];
#pragma unroll
        for (int mt = 0; mt < 5; ++mt) {
            O[mt][0] = (f32x4){0.f, 0.f, 0.f, 0.f};
            O[mt][1] = (f32x4){0.f, 0.f, 0.f, 0.f};
        }
#pragma unroll
        for (int nt2 = 0; nt2 < 2; ++nt2) {
#pragma unroll
            for (int kt = 0; kt < 3; ++kt) {
                const bool dead = (kt == 2) && (kg >= 2);
                int off = kt * 32 + kg * 8;
                if (off >= 80) off = 0;                // clamp: keep read in-bounds
                bf16x8 bv = *(const bf16x8*)(Vt + (nt2 * 16 + ln) * 88 + off);
                if (dead) {
#pragma unroll
                    for (int j = 0; j < 8; ++j) bv[j] = (bf16_t)0.f;
                }
                int cb = kt * 32 + kg * 8;
                if (cb >= 80) cb = 0;                  // clamp: finite a * zero b = 0
#pragma unroll
                for (int mt = 0; mt < 5; ++mt) {
                    bf16x8 av = *(const bf16x8*)(P + (mt * 16 + ln) * 88 + cb);
                    O[mt][nt2] = __builtin_amdgcn_mfma_f32_16x16x32_bf16(av, bv, O[mt][nt2], 0, 0, 0);
                }
            }
        }
#pragma unroll
        for (int mt = 0; mt < 5; ++mt)
#pragma unroll
            for (int nt2 = 0; nt2 < 2; ++nt2)
#pragma unroll
                for (int r = 0; r < 4; ++r) {
                    int n = mt * 16 + kg * 4 + r;
                    out[((size_t)w * 80 + n) * 256 + h * 32 + nt2 * 16 + ln] = (bf16_t)O[mt][nt2][r];
                }
    }
}

// ---------------- launch ----------------
extern "C" void kernel_launch(void* const* d_in, const int* in_sizes, int n_in,
                              void* d_out, int out_size, void* d_ws, size_t ws_size,
                              hipStream_t stream)
{
    (void)in_sizes; (void)n_in; (void)out_size; (void)ws_size;
    const float* x     = (const float*)d_in[0];
    const float* n1g   = (const float*)d_in[1];
    const float* n1b   = (const float*)d_in[2];
    const float* qkvw  = (const float*)d_in[3];
    const float* qkvb  = (const float*)d_in[4];
    const float* projw = (const float*)d_in[5];
    const float* projb = (const float*)d_in[6];
    const float* ls1   = (const float*)d_in[7];
    const float* n2g   = (const float*)d_in[8];
    const float* n2b   = (const float*)d_in[9];
    const float* fc1w  = (const float*)d_in[10];
    const float* fc1b  = (const float*)d_in[11];
    const float* fc2w  = (const float*)d_in[12];
    const float* fc2b  = (const float*)d_in[13];
    const float* ls2   = (const float*)d_in[14];
    float* out = (float*)d_out;

    // ws (bytes): [0,42MB) actA: ln1p -> attno -> ln2 (sequential reuse)
    //             [42,210MB) big: qkv plain 126MB -> h1 plain 168MB (sequential reuse)
    //             [210MB,..) transposed bf16 weights ~1.5MB
    char* ws = (char*)d_ws;
    bf16_t* actA   = (bf16_t*)(ws);
    bf16_t* qkv    = (bf16_t*)(ws + 41943040ull);
    bf16_t* h1     = (bf16_t*)(ws + 41943040ull);
    bf16_t* wbuf   = (bf16_t*)(ws + 209715200ull);
    bf16_t* qkvwt  = wbuf;                          // [768][256]
    bf16_t* projwt = qkvwt + 768 * 256;             // [256][256]
    bf16_t* fc1wt  = projwt + 256 * 256;            // [1024][256]
    bf16_t* fc2wt  = fc1wt + 1024 * 256;            // [256][1024]

    wconv_k<<<768,  256, 0, stream>>>(qkvw,  qkvwt, 768, 256);
    wconv_k<<<256,  256, 0, stream>>>(projw, projwt, 256, 256);
    wconv_k<<<1024, 256, 0, stream>>>(fc1w,  fc1wt, 1024, 256);
    wconv_k<<<1024, 256, 0, stream>>>(fc2w,  fc2wt, 256, 1024);

    ln_k<1><<<20480, 256, 0, stream>>>(x, n1g, n1b, actA);
    gq_k<<<3840, 256, 0, stream>>>(actA, qkvwt, qkvb, qkv, 768, 256);   // 640 x 6
    attn_k<<<1024, 256, 0, stream>>>(qkv, actA);
    gp_k<<<1280, 256, 0, stream>>>(actA, projwt, projb, x, ls1, out, 256, 256);   // 640 x 2
    ln_k<0><<<20480, 256, 0, stream>>>(out, n2g, n2b, actA);
    g1_k<<<5120, 256, 0, stream>>>(actA, fc1wt, fc1b, h1, 1024, 256);   // 640 x 8
    g2_k<<<1280, 256, 0, stream>>>(h1, fc2wt, fc2b, ls2, out, 256, 1024);   // 640 x 2
}

// Round 15
// 400.201 us; speedup vs baseline: 1.3596x; 1.0123x over previous
//
#include <hip/hip_runtime.h>
#include <hip/hip_bf16.h>
#include <stdint.h>
#include <math.h>

typedef __bf16 bf16_t;
typedef __bf16 bf16x8 __attribute__((ext_vector_type(8)));
typedef __bf16 bf16x4 __attribute__((ext_vector_type(4)));
typedef float  f32x4  __attribute__((ext_vector_type(4)));
typedef long long i64_t;

typedef __attribute__((address_space(1))) const void global_cv;
typedef __attribute__((address_space(3))) void lds_v;

// Problem constants: B=16,H=64,W=80,C=256; GH=8,GW=10; heads=8,DH=32; INNER=1024

__device__ __forceinline__ int map_p_to_g(int p) {
    int w = p / 80, n = p - w * 80;
    int b  = w >> 6, h2 = (w >> 3) & 7, w2 = w & 7;
    int gh = n / 10, gw = n - gh * 10;
    return b * 5120 + (gh * 8 + h2) * 80 + (gw * 8 + w2);
}

// XOR swizzle for 128-B LDS rows: bits 4-6 ^= bits 7-9 (involution, keeps 16B align)
__device__ __forceinline__ int swz128(int b) { return b ^ (((b >> 7) & 7) << 4); }

// ---------------- weight convert+transpose: fp32 [K][N] -> bf16 [N][K] ----------------
__global__ __launch_bounds__(256) void wconv_k(const float* __restrict__ in,
                                               bf16_t* __restrict__ out, int N, int K)
{
    int i = blockIdx.x * 256 + threadIdx.x;
    int n = i / K, k = i - n * K;
    out[i] = (bf16_t)in[(size_t)k * N + n];
}

// ---------------- fc2 weight convert: fp32 [1024][256] -> fp8 e4m3 [256][1024], x16 ----------------
__global__ __launch_bounds__(256) void wconv8_k(const float* __restrict__ in,
                                                unsigned char* __restrict__ out)
{
    int c  = blockIdx.x * 256 + threadIdx.x;   // 4 consecutive k for one n; grid 256
    int n  = (c * 4) >> 10;
    int k0 = (c * 4) & 1023;
    float g0 = 16.f * in[(size_t)(k0 + 0) * 256 + n];
    float g1 = 16.f * in[(size_t)(k0 + 1) * 256 + n];
    float g2 = 16.f * in[(size_t)(k0 + 2) * 256 + n];
    float g3 = 16.f * in[(size_t)(k0 + 3) * 256 + n];
    int pk = __builtin_amdgcn_cvt_pk_fp8_f32(g0, g1, 0, false);
    pk     = __builtin_amdgcn_cvt_pk_fp8_f32(g2, g3, pk, true);
    *(int*)(out + (size_t)c * 4) = pk;
}

// ---------------- LayerNorm (one wave per row), optional partition permute ----------------
template <int PERM>
__global__ __launch_bounds__(256) void ln_k(const float* __restrict__ in,
                                            const float* __restrict__ gg,
                                            const float* __restrict__ bb,
                                            bf16_t* __restrict__ o)
{
    int row  = blockIdx.x * 4 + (threadIdx.x >> 6);
    int lane = threadIdx.x & 63;
    const float4 xv = *(const float4*)(in + (size_t)row * 256 + lane * 4);
    float s = xv.x + xv.y + xv.z + xv.w;
#pragma unroll
    for (int m = 1; m < 64; m <<= 1) s += __shfl_xor(s, m, 64);
    float mean = s * (1.f / 256.f);
    float d0 = xv.x - mean, d1 = xv.y - mean, d2 = xv.z - mean, d3 = xv.w - mean;
    float v = d0 * d0 + d1 * d1 + d2 * d2 + d3 * d3;
#pragma unroll
    for (int m = 1; m < 64; m <<= 1) v += __shfl_xor(v, m, 64);
    float rstd = rsqrtf(v * (1.f / 256.f) + 1e-5f);
    const float4 gv = *(const float4*)(gg + lane * 4);
    const float4 bv = *(const float4*)(bb + lane * 4);
    int orow = row;
    if (PERM) {
        int b = row / 5120, r1 = row - b * 5120;
        int h = r1 / 80, wv = r1 - h * 80;
        int gh = h >> 3, h2 = h & 7, gw = wv >> 3, w2 = wv & 7;
        orow = ((b * 8 + h2) * 8 + w2) * 80 + gh * 10 + gw;
    }
    bf16x4 ov;
    ov[0] = (bf16_t)(d0 * rstd * gv.x + bv.x);
    ov[1] = (bf16_t)(d1 * rstd * gv.y + bv.y);
    ov[2] = (bf16_t)(d2 * rstd * gv.z + bv.z);
    ov[3] = (bf16_t)(d3 * rstd * gv.w + bv.w);
    *(bf16x4*)(o + (size_t)orow * 256 + lane * 4) = ov;
}

// ---------------- 128x128-tile MFMA GEMM, high-occupancy (r13/r14, unchanged core) ----------------
// EPI 0: bf16 out (+bias) [qkv]; 1: fp32 x[g]+ls*(acc+b), grid-reverse [proj];
// EPI 2: fp8 out = 16*gelu_sig(acc+bias) [fc1]
template <int EPI, int NBX>
__device__ __forceinline__ void gemm_body(const bf16_t* __restrict__ A,
                                          const bf16_t* __restrict__ Bt,
                                          const float* __restrict__ bias,
                                          const float* __restrict__ xres,
                                          const float* __restrict__ ls,
                                          void* __restrict__ outp,
                                          int N, int K)
{
    __shared__ bf16_t At[128 * 64];   // 16 KB: 128 rows x 128 B, swizzled content
    __shared__ bf16_t Bl[128 * 64];
    const int t = threadIdx.x;
    const int wid = t >> 6, lane = t & 63;
    const int wr = wid >> 1, wc = wid & 1;
    const int ln = lane & 15, kg = lane >> 4;

    const int f   = blockIdx.x;
    const int xcd = f & 7, jj = f >> 3;
    const int byx = (gridDim.x >> 3) / NBX;
    const int by  = xcd * byx + jj / NBX;
    const int bx  = jj % NBX;

    const size_t Kb = (size_t)K * 2;
    const char* Ab = (const char*)(A  + (size_t)by * 128 * K);
    const char* Bb = (const char*)(Bt + (size_t)bx * 128 * K);
    char* AtB = (char*)At;
    char* BlB = (char*)Bl;

    const f32x4 fz = {0.f, 0.f, 0.f, 0.f};
    f32x4 acc[4][4];
#pragma unroll
    for (int i = 0; i < 4; ++i)
#pragma unroll
        for (int j = 0; j < 4; ++j) acc[i][j] = fz;

    const int nsteps = K >> 6;

    for (int s = 0; s < nsteps; ++s) {
        const size_t kb = (size_t)s * 128;
#pragma unroll
        for (int i = 0; i < 4; ++i) {
            int p   = (i * 256 + t) * 16;
            int row = p >> 7;
            int off = (p & 127) ^ ((row & 7) << 4);   // inverse-swizzled source
            __builtin_amdgcn_global_load_lds((global_cv*)(Ab + (size_t)row * Kb + kb + off),
                                             (lds_v*)(AtB + p), 16, 0, 0);
            __builtin_amdgcn_global_load_lds((global_cv*)(Bb + (size_t)row * Kb + kb + off),
                                             (lds_v*)(BlB + p), 16, 0, 0);
        }
        __syncthreads();
#pragma unroll
        for (int kk = 0; kk < 2; ++kk) {
            bf16x8 av[4], bv[4];
#pragma unroll
            for (int mt = 0; mt < 4; ++mt) {
                int row = wr * 64 + mt * 16 + ln;
                av[mt] = *(const bf16x8*)(AtB + swz128(row * 128 + kk * 64 + kg * 16));
            }
#pragma unroll
            for (int nt = 0; nt < 4; ++nt) {
                int row = wc * 64 + nt * 16 + ln;
                bv[nt] = *(const bf16x8*)(BlB + swz128(row * 128 + kk * 64 + kg * 16));
            }
            // swapped operands: D^T layout -> our row=ln, our cols=kg*4+r
#pragma unroll
            for (int mt = 0; mt < 4; ++mt)
#pragma unroll
                for (int nt = 0; nt < 4; ++nt)
                    acc[mt][nt] = __builtin_amdgcn_mfma_f32_16x16x32_bf16(bv[nt], av[mt], acc[mt][nt], 0, 0, 0);
        }
        __syncthreads();
    }

#pragma unroll
    for (int mt = 0; mt < 4; ++mt) {
        const int row = by * 128 + wr * 64 + mt * 16 + ln;
#pragma unroll
        for (int nt = 0; nt < 4; ++nt) {
            const int colb = bx * 128 + wc * 64 + nt * 16 + kg * 4;
            const f32x4 a = acc[mt][nt];   // a[r] -> col colb+r
            const float4 b4 = *(const float4*)(bias + colb);
            if constexpr (EPI == 0) {
                bf16_t* o = (bf16_t*)outp;
                bf16x4 ov;
                ov[0] = (bf16_t)(a[0] + b4.x); ov[1] = (bf16_t)(a[1] + b4.y);
                ov[2] = (bf16_t)(a[2] + b4.z); ov[3] = (bf16_t)(a[3] + b4.w);
                *(bf16x4*)(o + (size_t)row * N + colb) = ov;
            } else if constexpr (EPI == 1) {
                const float4 l4 = *(const float4*)(ls + colb);
                float* o = (float*)outp;
                int g = map_p_to_g(row);
                size_t idx = (size_t)g * 256 + colb;
                float4 xr = *(const float4*)(xres + idx);
                float4 r4;
                r4.x = xr.x + l4.x * (a[0] + b4.x);
                r4.y = xr.y + l4.y * (a[1] + b4.y);
                r4.z = xr.z + l4.z * (a[2] + b4.z);
                r4.w = xr.w + l4.w * (a[3] + b4.w);
                *(float4*)(o + idx) = r4;
            } else {   // EPI == 2: fc1 -> fp8 h1 (x16)
                unsigned char* o = (unsigned char*)outp;
                float g4[4];
#pragma unroll
                for (int r = 0; r < 4; ++r) {
                    float u2 = a[r] + ((const float*)&b4)[r];
                    // GELU ~= u*sigmoid(1.702u); err ~0.02 ~ bf16 rounding of h1,
                    // x1e-5 downstream -> ~1e-7 at output. NaN-safe at +-inf.
                    float gl = u2 / (1.f + __expf(-1.702f * u2));
                    g4[r] = 16.f * gl;      // e4m3 normal range; undone by 1/256 in g2f8
                }
                int pk = __builtin_amdgcn_cvt_pk_fp8_f32(g4[0], g4[1], 0, false);
                pk     = __builtin_amdgcn_cvt_pk_fp8_f32(g4[2], g4[3], pk, true);
                *(int*)(o + (size_t)row * N + colb) = pk;
            }
        }
    }
}

__global__ __launch_bounds__(256, 4) void gq_k(const bf16_t* A, const bf16_t* Bt, const float* bias,
                                               void* outp, int N, int K)
{ gemm_body<0, 6>(A, Bt, bias, nullptr, nullptr, outp, N, K); }

__global__ __launch_bounds__(256, 4) void gp_k(const bf16_t* A, const bf16_t* Bt, const float* bias,
                                               const float* xres, const float* ls, void* outp, int N, int K)
{ gemm_body<1, 2>(A, Bt, bias, xres, ls, outp, N, K); }

__global__ __launch_bounds__(256, 4) void g1_k(const bf16_t* A, const bf16_t* Bt, const float* bias,
                                               void* outp, int N, int K)
{ gemm_body<2, 8>(A, Bt, bias, nullptr, nullptr, outp, N, K); }

// ---------------- fc2 GEMM in fp8: out += ls2*(acc/256 + b2) ----------------
// A = h1 fp8 [81920][1024], Bt = fc2w fp8 [256][1024] (both x16-scaled).
// 128x128 tile, BK=64 (64-B rows), 16-B-granule XOR swizzle (row&3)<<4 both sides.
// Fragments: ds_read_b64 (8 fp8/lane), mfma_f32_16x16x32_fp8_fp8 swapped operands.
__global__ __launch_bounds__(256, 4) void g2f8_k(const unsigned char* __restrict__ A,
                                                 const unsigned char* __restrict__ Bt,
                                                 const float* __restrict__ bias,
                                                 const float* __restrict__ ls,
                                                 float* __restrict__ out)
{
    __shared__ __align__(16) char At[8192];   // 128 rows x 64 B
    __shared__ __align__(16) char Bl[8192];
    const int t = threadIdx.x;
    const int wid = t >> 6, lane = t & 63;
    const int wr = wid >> 1, wc = wid & 1;
    const int ln = lane & 15, kg = lane >> 4;

    const int f   = blockIdx.x;
    const int xcd = f & 7, jj = f >> 3;
    const int byx = (gridDim.x >> 3) / 2;
    const int by  = xcd * byx + jj / 2;
    const int bx  = jj & 1;

    const char* Ab = (const char*)A  + (size_t)by * 128 * 1024;
    const char* Bb = (const char*)Bt + (size_t)bx * 128 * 1024;

    const f32x4 fz = {0.f, 0.f, 0.f, 0.f};
    f32x4 acc[4][4];
#pragma unroll
    for (int i = 0; i < 4; ++i)
#pragma unroll
        for (int j = 0; j < 4; ++j) acc[i][j] = fz;

    for (int s = 0; s < 16; ++s) {
        const size_t kb = (size_t)s * 64;
#pragma unroll
        for (int i = 0; i < 2; ++i) {
            int p   = (i * 256 + t) * 16;
            int row = p >> 6;
            int off = (p & 63) ^ ((row & 3) << 4);   // inverse-swizzled source
            __builtin_amdgcn_global_load_lds((global_cv*)(Ab + (size_t)row * 1024 + kb + off),
                                             (lds_v*)(At + p), 16, 0, 0);
            __builtin_amdgcn_global_load_lds((global_cv*)(Bb + (size_t)row * 1024 + kb + off),
                                             (lds_v*)(Bl + p), 16, 0, 0);
        }
        __syncthreads();
#pragma unroll
        for (int kk = 0; kk < 2; ++kk) {
            i64_t av[4], bv[4];
#pragma unroll
            for (int mt = 0; mt < 4; ++mt) {
                int row = wr * 64 + mt * 16 + ln;
                av[mt] = *(const i64_t*)(At + row * 64 + ((kk * 32 + kg * 8) ^ ((row & 3) << 4)));
            }
#pragma unroll
            for (int nt = 0; nt < 4; ++nt) {
                int row = wc * 64 + nt * 16 + ln;
                bv[nt] = *(const i64_t*)(Bl + row * 64 + ((kk * 32 + kg * 8) ^ ((row & 3) << 4)));
            }
            // swapped operands: D^T layout -> our row=ln, our cols=kg*4+r
#pragma unroll
            for (int mt = 0; mt < 4; ++mt)
#pragma unroll
                for (int nt = 0; nt < 4; ++nt)
                    acc[mt][nt] = __builtin_amdgcn_mfma_f32_16x16x32_fp8_fp8(bv[nt], av[mt], acc[mt][nt], 0, 0, 0);
        }
        __syncthreads();
    }

#pragma unroll
    for (int mt = 0; mt < 4; ++mt) {
        const int row = by * 128 + wr * 64 + mt * 16 + ln;
#pragma unroll
        for (int nt = 0; nt < 4; ++nt) {
            const int colb = bx * 128 + wc * 64 + nt * 16 + kg * 4;
            const f32x4 a = acc[mt][nt];
            const float4 b4 = *(const float4*)(bias + colb);
            const float4 l4 = *(const float4*)(ls + colb);
            size_t idx = (size_t)row * 256 + colb;
            float4 cur = *(const float4*)(out + idx);
            cur.x += l4.x * (a[0] * 0.00390625f + b4.x);   // 1/256 undoes the two x16 scales
            cur.y += l4.y * (a[1] * 0.00390625f + b4.y);
            cur.z += l4.z * (a[2] * 0.00390625f + b4.z);
            cur.w += l4.w * (a[3] * 0.00390625f + b4.w);
            *(float4*)(out + idx) = cur;
        }
    }
}

// ---------------- fused per-window attention (r14, unchanged) ----------------
__global__ __launch_bounds__(256) void attn_k(const bf16_t* __restrict__ qkv,
                                              bf16_t* __restrict__ out)
{
    __shared__ bf16_t Slds[4 * 9888];     // per wave: P 7040 + Vt 2816 + pad 32
    const int t = threadIdx.x, wid = t >> 6, lane = t & 63;
    const int ln = lane & 15, kg = lane >> 4;
    bf16_t* P  = &Slds[wid * 9888];
    bf16_t* Vt = P + 7040;
    const int w = blockIdx.x;
    const bf16_t* base = qkv + (size_t)w * 80 * 768;
    const float SCALE = 0.17677669529663689f;

    for (int hh = 0; hh < 2; ++hh) {
        const int h = wid + hh * 4;
        const bf16_t* hb = base + h * 96;

        // ---- stage V transposed: Vt[d][tok], rows 88 elems (176 B, 16B-aligned)
#pragma unroll
        for (int half = 0; half < 2; ++half) {
            int tok = half * 64 + lane;
            if (tok < 80) {
                const bf16_t* vr = hb + (size_t)tok * 768 + 64;
#pragma unroll
                for (int q8 = 0; q8 < 4; ++q8) {
                    bf16x8 v = *(const bf16x8*)(vr + q8 * 8);
#pragma unroll
                    for (int j = 0; j < 8; ++j)
                        Vt[(q8 * 8 + j) * 88 + tok] = v[j];
                }
            }
        }

        // ---- S = Q K^T
        bf16x8 qa[5], kb[5];
#pragma unroll
        for (int mt = 0; mt < 5; ++mt)
            qa[mt] = *(const bf16x8*)(hb + (size_t)(mt * 16 + ln) * 768 + kg * 8);
#pragma unroll
        for (int nt = 0; nt < 5; ++nt)
            kb[nt] = *(const bf16x8*)(hb + (size_t)(nt * 16 + ln) * 768 + 32 + kg * 8);
        f32x4 S[5][5];
#pragma unroll
        for (int mt = 0; mt < 5; ++mt)
#pragma unroll
            for (int nt = 0; nt < 5; ++nt) {
                f32x4 z = {0.f, 0.f, 0.f, 0.f};
                S[mt][nt] = __builtin_amdgcn_mfma_f32_16x16x32_bf16(qa[mt], kb[nt], z, 0, 0, 0);
            }
        // ---- softmax over rows
#pragma unroll
        for (int mt = 0; mt < 5; ++mt) {
#pragma unroll
            for (int r = 0; r < 4; ++r) {
                float mx = S[mt][0][r];
#pragma unroll
                for (int nt = 1; nt < 5; ++nt) mx = fmaxf(mx, S[mt][nt][r]);
                mx = fmaxf(mx, __shfl_xor(mx, 1, 64));
                mx = fmaxf(mx, __shfl_xor(mx, 2, 64));
                mx = fmaxf(mx, __shfl_xor(mx, 4, 64));
                mx = fmaxf(mx, __shfl_xor(mx, 8, 64));
                float sum = 0.f;
#pragma unroll
                for (int nt = 0; nt < 5; ++nt) {
                    float e = __expf((S[mt][nt][r] - mx) * SCALE);
                    S[mt][nt][r] = e;
                    sum += e;
                }
                sum += __shfl_xor(sum, 1, 64);
                sum += __shfl_xor(sum, 2, 64);
                sum += __shfl_xor(sum, 4, 64);
                sum += __shfl_xor(sum, 8, 64);
                float inv = 1.f / sum;
#pragma unroll
                for (int nt = 0; nt < 5; ++nt) S[mt][nt][r] *= inv;
            }
        }
        // ---- P -> LDS (D-layout scatter), consumed as A-operand
#pragma unroll
        for (int mt = 0; mt < 5; ++mt)
#pragma unroll
            for (int nt = 0; nt < 5; ++nt)
#pragma unroll
                for (int r = 0; r < 4; ++r)
                    P[(mt * 16 + kg * 4 + r) * 88 + nt * 16 + ln] = (bf16_t)S[mt][nt][r];
        // ---- O = P V ; V^T fragments via 16-B ds_reads from Vt
        f32x4 O[5][2];
#pragma unroll
        for (int mt = 0; mt < 5; ++mt) {
            O[mt][0] = (f32x4){0.f, 0.f, 0.f, 0.f};
            O[mt][1] = (f32x4){0.f, 0.f, 0.f, 0.f};
        }
#pragma unroll
        for (int nt2 = 0; nt2 < 2; ++nt2) {
#pragma unroll
            for (int kt = 0; kt < 3; ++kt) {
                const bool dead = (kt == 2) && (kg >= 2);
                int off = kt * 32 + kg * 8;
                if (off >= 80) off = 0;
                bf16x8 bv = *(const bf16x8*)(Vt + (nt2 * 16 + ln) * 88 + off);
                if (dead) {
#pragma unroll
                    for (int j = 0; j < 8; ++j) bv[j] = (bf16_t)0.f;
                }
                int cb = kt * 32 + kg * 8;
                if (cb >= 80) cb = 0;
#pragma unroll
                for (int mt = 0; mt < 5; ++mt) {
                    bf16x8 av = *(const bf16x8*)(P + (mt * 16 + ln) * 88 + cb);
                    O[mt][nt2] = __builtin_amdgcn_mfma_f32_16x16x32_bf16(av, bv, O[mt][nt2], 0, 0, 0);
                }
            }
        }
#pragma unroll
        for (int mt = 0; mt < 5; ++mt)
#pragma unroll
            for (int nt2 = 0; nt2 < 2; ++nt2)
#pragma unroll
                for (int r = 0; r < 4; ++r) {
                    int n = mt * 16 + kg * 4 + r;
                    out[((size_t)w * 80 + n) * 256 + h * 32 + nt2 * 16 + ln] = (bf16_t)O[mt][nt2][r];
                }
    }
}

// ---------------- launch ----------------
extern "C" void kernel_launch(void* const* d_in, const int* in_sizes, int n_in,
                              void* d_out, int out_size, void* d_ws, size_t ws_size,
                              hipStream_t stream)
{
    (void)in_sizes; (void)n_in; (void)out_size; (void)ws_size;
    const float* x     = (const float*)d_in[0];
    const float* n1g   = (const float*)d_in[1];
    const float* n1b   = (const float*)d_in[2];
    const float* qkvw  = (const float*)d_in[3];
    const float* qkvb  = (const float*)d_in[4];
    const float* projw = (const float*)d_in[5];
    const float* projb = (const float*)d_in[6];
    const float* ls1   = (const float*)d_in[7];
    const float* n2g   = (const float*)d_in[8];
    const float* n2b   = (const float*)d_in[9];
    const float* fc1w  = (const float*)d_in[10];
    const float* fc1b  = (const float*)d_in[11];
    const float* fc2w  = (const float*)d_in[12];
    const float* fc2b  = (const float*)d_in[13];
    const float* ls2   = (const float*)d_in[14];
    float* out = (float*)d_out;

    // ws (bytes): [0,42MB) actA: ln1p -> attno -> ln2 (sequential reuse)
    //             [42,210MB) big: qkv plain 126MB -> h1 fp8 84MB (sequential reuse)
    //             [210MB,..) weights: bf16 ~1MB + fp8 fc2w 256KB
    char* ws = (char*)d_ws;
    bf16_t* actA   = (bf16_t*)(ws);
    bf16_t* qkv    = (bf16_t*)(ws + 41943040ull);
    unsigned char* h1f8 = (unsigned char*)(ws + 41943040ull);
    bf16_t* wbuf   = (bf16_t*)(ws + 209715200ull);
    bf16_t* qkvwt  = wbuf;                          // [768][256]
    bf16_t* projwt = qkvwt + 768 * 256;             // [256][256]
    bf16_t* fc1wt  = projwt + 256 * 256;            // [1024][256]
    unsigned char* fc2w8 = (unsigned char*)(fc1wt + 1024 * 256);   // fp8 [256][1024]

    wconv_k<<<768,  256, 0, stream>>>(qkvw,  qkvwt, 768, 256);
    wconv_k<<<256,  256, 0, stream>>>(projw, projwt, 256, 256);
    wconv_k<<<1024, 256, 0, stream>>>(fc1w,  fc1wt, 1024, 256);
    wconv8_k<<<256, 256, 0, stream>>>(fc2w, fc2w8);

    ln_k<1><<<20480, 256, 0, stream>>>(x, n1g, n1b, actA);
    gq_k<<<3840, 256, 0, stream>>>(actA, qkvwt, qkvb, qkv, 768, 256);   // 640 x 6
    attn_k<<<1024, 256, 0, stream>>>(qkv, actA);
    gp_k<<<1280, 256, 0, stream>>>(actA, projwt, projb, x, ls1, out, 256, 256);   // 640 x 2
    ln_k<0><<<20480, 256, 0, stream>>>(out, n2g, n2b, actA);
    g1_k<<<5120, 256, 0, stream>>>(actA, fc1wt, fc1b, h1f8, 1024, 256);   // 640 x 8
    g2f8_k<<<1280, 256, 0, stream>>>(h1f8, fc2w8, fc2b, ls2, out);        // 640 x 2
}